// Round 6
// baseline (10794.615 us; speedup 1.0000x reference)
//
#include <hip/hip_runtime.h>
#include <math.h>

#define HID    512
#define BATCH  512
#define TIN    512
#define TOUT   128
#define FOUR_H 2048
#define STEPS  (TIN + TOUT)

typedef __bf16 bf16x8 __attribute__((ext_vector_type(8)));
typedef float floatx4 __attribute__((ext_vector_type(4)));
typedef int   int4v   __attribute__((ext_vector_type(4)));

// LLC-direct (bypass L1+L2) 16-B load/store (coherence point = Infinity Cache).
#define GLOADX4(dst, p) \
    asm volatile("global_load_dwordx4 %0, %1, off sc0 sc1" : "=v"(dst) : "v"(p))
#define GSTOREX4(p, v) \
    asm volatile("global_store_dwordx4 %0, %1, off sc0 sc1" :: "v"(p), "v"(v) : "memory")
// exact-count waits; ties the 8 consumed buffers so MFMA can't be hoisted above
#define WAITVN(N, B) \
    asm volatile("s_waitcnt vmcnt(" #N ")" \
        : "+v"((B)[0]), "+v"((B)[1]), "+v"((B)[2]), "+v"((B)[3]), \
          "+v"((B)[4]), "+v"((B)[5]), "+v"((B)[6]), "+v"((B)[7]))

__device__ __forceinline__ float fsig(float x) {
    return __builtin_amdgcn_rcpf(1.0f + __expf(-x));
}
__device__ __forceinline__ float ftanh(float x) {
    return 1.0f - 2.0f * __builtin_amdgcn_rcpf(1.0f + __expf(2.0f * x));
}

// ---------- prep: pack Whh into MFMA-fragment order, bf16 hi/lo planes.
// Element (plane, m', k), m' = 4*j+g (row r = g*512+j of W):
//   mx=m'>>6, w=(m'>>4)&3, lr=m'&15, chunk=k>>5, lq=(k>>3)&3, lane=lq*16+lr
//   elem-offset = (mx*128 + w*32 + chunk*2 + plane)*512 + lane*8
// K-loop ds_read: lds[w*16384 + chunk*1024 + plane*512 + lane*8] ->
// bank = 4*lane mod 32 -> conflict-free ds_read_b128.
// (hand-verified: W[516][40] -> elem 17544 -> lane 17 (lq=1,lr=1), chunk 1,
//  which is exactly A[m=1][k=40] in the 16x16x32 A-fragment layout)
__global__ __launch_bounds__(256) void pack_w(
    const float* __restrict__ W, __bf16* __restrict__ Apk)
{
    int tid = blockIdx.x * 256 + threadIdx.x;   // 131072 threads
    int mp  = tid >> 6;                         // m' in [0,2048)
    int kg  = tid & 63;                         // k-group of 8
    int g   = mp & 3;
    int j   = mp >> 2;
    int r   = g * HID + j;
    int mx    = mp >> 6;
    int w     = (mp >> 4) & 3;
    int lr    = mp & 15;
    int chunk = kg >> 2;
    int lq    = kg & 3;
    int lane  = lq * 16 + lr;
    const float* src = W + (size_t)r * HID + kg * 8;
    size_t offHi = ((size_t)(mx * 128 + w * 32 + chunk * 2 + 0) * 512) + lane * 8;
    size_t offLo = ((size_t)(mx * 128 + w * 32 + chunk * 2 + 1) * 512) + lane * 8;
    __bf16 hibuf[8], lobuf[8];
    #pragma unroll
    for (int i = 0; i < 8; ++i) {
        float x = src[i];
        __bf16 hi = (__bf16)x;
        hibuf[i] = hi;
        lobuf[i] = (__bf16)(x - (float)hi);
    }
    *(bf16x8*)(Apk + offHi) = *(bf16x8*)hibuf;
    *(bf16x8*)(Apk + offLo) = *(bf16x8*)lobuf;
}

__global__ __launch_bounds__(256) void pack_v(
    const float* __restrict__ Wih, const float* __restrict__ b,
    float* __restrict__ WihP, float* __restrict__ bP)
{
    int mp = blockIdx.x * 256 + threadIdx.x;
    int g  = mp & 3;
    int j  = mp >> 2;
    int r  = g * HID + j;
    WihP[mp] = Wih[r];
    bP[mp]   = b[r];
}

__global__ __launch_bounds__(256) void transpose_in(
    const float* __restrict__ in, float* __restrict__ outT)
{
    int idx = blockIdx.x * 256 + threadIdx.x;
    int t = idx >> 9, b = idx & 511;
    outT[idx] = in[(size_t)b * TIN + t];
}

// ---------- persistent cooperative kernel ----------
// grid 256 = 32 mx x 8 by; block 256 = 4 waves; 1 block/CU (LDS-limited).
// h exchange LLC-direct (sc0 sc1); barrier relaxed device-scope atomics (no
// wbl2/inv -- R3->R4 proved cache-maintenance ops were the 30 ms tax).
// Pipeline kept at 3-deep / 4 buffers (128 buffer VGPRs) so total VGPR stays
// in the <=256 granule: R5's 5-deep (~300 VGPR) variant never launched.
__global__ __launch_bounds__(256, 1) void lstm_persistent(
    const __bf16* __restrict__ ApkEnc,   // [32][128][512] bf16 fragment order, 4 MB
    const __bf16* __restrict__ ApkDec,
    const float* __restrict__ WihPenc, const float* __restrict__ biasPenc,
    const float* __restrict__ WihPdec, const float* __restrict__ biasPdec,
    const float* __restrict__ inputsT,
    const float* __restrict__ linW, const float* __restrict__ linb,
    __bf16* __restrict__ h0hi, __bf16* __restrict__ h0lo,
    __bf16* __restrict__ h1hi, __bf16* __restrict__ h1lo,
    float* __restrict__ xacc,        // [3][BATCH] rotating decoder-feedback accum
    int* __restrict__ barrier_ws,
    float* __restrict__ out)         // [BATCH][TOUT]
{
    extern __shared__ char smem[];
    __bf16* Alds = (__bf16*)smem;                        // 131072 B, fragment order
    __bf16* hstage = (__bf16*)(smem + 131072);           // [2][64][16] = 4096 B
    float*  xred = (float*)(smem + 131072 + 4096);       // [64]

    const int tid  = threadIdx.x;
    const int lane = tid & 63;
    const int w    = tid >> 6;
    const int lr   = lane & 15;
    const int lq   = lane >> 4;
    const int by   = blockIdx.x & 7;
    const int mx   = blockIdx.x >> 3;
    const int nbase = by * 64;
    const int mrow0 = mx * 64;
    const int m0    = mrow0 + w * 16 + lq * 4;   // lane's 4 m' rows (C-layout)
    const int jl    = w * 4 + lq;                // local j 0..15

    const floatx4 wihE = *(const floatx4*)(WihPenc + m0);
    const floatx4 bE   = *(const floatx4*)(biasPenc + m0);
    const floatx4 wihD = *(const floatx4*)(WihPdec + m0);
    const floatx4 bD   = *(const floatx4*)(biasPdec + m0);
    const float lw = linW[mx * 16 + jl];
    const float lb = linb[0];

    int bn[4];
    #pragma unroll
    for (int nt = 0; nt < 4; ++nt) bn[nt] = nbase + nt * 16 + lr;

    // stage encoder weights: linear 128 KB copy (normal cached loads, read-only)
    {
        const int4v* srcp = (const int4v*)(ApkEnc + (size_t)mx * 65536);
        int4v* dstp = (int4v*)Alds;
        for (int i = tid; i < 8192; i += 256) dstp[i] = srcp[i];
    }
    __syncthreads();

    float creg[4] = {0.f, 0.f, 0.f, 0.f};

    int* arrive = barrier_ws + by * 32;
    int* phase  = barrier_ws + 512 + by * 32;

    // per-lane LDS fragment base: [w][chunk][plane][lane]*16B
    const __bf16* aBase = Alds + (size_t)w * 16384 + (size_t)lane * 8;

    for (int s = 0; s < STEPS; ++s) {
        const bool dec = (s >= TIN);
        const int  t   = s - TIN;

        if (s == TIN) {
            const int4v* srcp = (const int4v*)(ApkDec + (size_t)mx * 65536);
            int4v* dstp = (int4v*)Alds;
            for (int i = tid; i < 8192; i += 256) dstp[i] = srcp[i];
            __syncthreads();
        }

        const __bf16* hinhi = (s & 1) ? h1hi : h0hi;
        const __bf16* hinlo = (s & 1) ? h1lo : h0lo;
        __bf16* houthi = (s & 1) ? h0hi : h1hi;
        __bf16* houtlo = (s & 1) ? h0lo : h1lo;

        // ---- B pointers; start the pipeline (3 chunks deep, 4 buffers) ----
        const __bf16* pB[8];
        #pragma unroll
        for (int nt = 0; nt < 4; ++nt) {
            pB[2 * nt]     = hinhi + (size_t)bn[nt] * HID + lq * 8;
            pB[2 * nt + 1] = hinlo + (size_t)bn[nt] * HID + lq * 8;
        }
        int4v buf[4][8];
        #pragma unroll
        for (int c = 0; c < 3; ++c) {
            #pragma unroll
            for (int i = 0; i < 8; ++i) GLOADX4(buf[c][i], pB[i] + c * 32);
        }

        // ---- x_t + decoder bookkeeping (overlaps load latency) ----
        float xq[4];
        if (dec) {
            if (tid < 64) xred[tid] = 0.f;
            if (mx == 0) {
                if (t >= 1 && tid < 64) {
                    float v = __hip_atomic_load(&xacc[((t - 1) % 3) * BATCH + nbase + tid],
                                                __ATOMIC_RELAXED, __HIP_MEMORY_SCOPE_AGENT) + lb;
                    out[(size_t)(nbase + tid) * TOUT + (t - 1)] = v;
                }
                if (tid >= 64 && tid < 128) {
                    __hip_atomic_store(&xacc[((t + 1) % 3) * BATCH + nbase + (tid - 64)], 0.0f,
                                       __ATOMIC_RELAXED, __HIP_MEMORY_SCOPE_AGENT);
                }
            }
            #pragma unroll
            for (int nt = 0; nt < 4; ++nt)
                xq[nt] = (t == 0) ? inputsT[(TIN - 1) * BATCH + bn[nt]]
                                  : __hip_atomic_load(&xacc[((t - 1) % 3) * BATCH + bn[nt]],
                                                      __ATOMIC_RELAXED, __HIP_MEMORY_SCOPE_AGENT) + lb;
        } else {
            #pragma unroll
            for (int nt = 0; nt < 4; ++nt)
                xq[nt] = inputsT[s * BATCH + bn[nt]];
        }

        floatx4 acc0 = {0,0,0,0}, acc1 = {0,0,0,0}, acc2 = {0,0,0,0}, acc3 = {0,0,0,0};

        // ---- K-loop: 16 chunks, 3-deep pipelined LLC loads, exact vmcnt ----
        // invariant: after wait(24) at iter it, completed >= 8*(it+4)+bk-24
        //            >= 8*it+8 -> chunk `it` fully resident.
        #pragma unroll
        for (int it = 0; it < 16; ++it) {
            if (it + 3 < 16) {
                int4v* nx = buf[(it + 3) & 3];
                #pragma unroll
                for (int i = 0; i < 8; ++i) GLOADX4(nx[i], pB[i] + (it + 3) * 32);
            }
            int4v* cur = buf[it & 3];
            if      (it <= 12) { WAITVN(24, cur); }
            else if (it == 13) { WAITVN(16, cur); }
            else if (it == 14) { WAITVN(8,  cur); }
            else               { WAITVN(0,  cur); }

            const __bf16* ap = aBase + it * 1024;
            bf16x8 ah = *(const bf16x8*)(ap);
            bf16x8 al = *(const bf16x8*)(ap + 512);
            bf16x8 bh0 = __builtin_bit_cast(bf16x8, cur[0]);
            bf16x8 bl0 = __builtin_bit_cast(bf16x8, cur[1]);
            bf16x8 bh1 = __builtin_bit_cast(bf16x8, cur[2]);
            bf16x8 bl1 = __builtin_bit_cast(bf16x8, cur[3]);
            bf16x8 bh2 = __builtin_bit_cast(bf16x8, cur[4]);
            bf16x8 bl2 = __builtin_bit_cast(bf16x8, cur[5]);
            bf16x8 bh3 = __builtin_bit_cast(bf16x8, cur[6]);
            bf16x8 bl3 = __builtin_bit_cast(bf16x8, cur[7]);

            acc0 = __builtin_amdgcn_mfma_f32_16x16x32_bf16(ah, bh0, acc0, 0, 0, 0);
            acc1 = __builtin_amdgcn_mfma_f32_16x16x32_bf16(ah, bh1, acc1, 0, 0, 0);
            acc2 = __builtin_amdgcn_mfma_f32_16x16x32_bf16(ah, bh2, acc2, 0, 0, 0);
            acc3 = __builtin_amdgcn_mfma_f32_16x16x32_bf16(ah, bh3, acc3, 0, 0, 0);
            acc0 = __builtin_amdgcn_mfma_f32_16x16x32_bf16(al, bh0, acc0, 0, 0, 0);
            acc1 = __builtin_amdgcn_mfma_f32_16x16x32_bf16(al, bh1, acc1, 0, 0, 0);
            acc2 = __builtin_amdgcn_mfma_f32_16x16x32_bf16(al, bh2, acc2, 0, 0, 0);
            acc3 = __builtin_amdgcn_mfma_f32_16x16x32_bf16(al, bh3, acc3, 0, 0, 0);
            acc0 = __builtin_amdgcn_mfma_f32_16x16x32_bf16(ah, bl0, acc0, 0, 0, 0);
            acc1 = __builtin_amdgcn_mfma_f32_16x16x32_bf16(ah, bl1, acc1, 0, 0, 0);
            acc2 = __builtin_amdgcn_mfma_f32_16x16x32_bf16(ah, bl2, acc2, 0, 0, 0);
            acc3 = __builtin_amdgcn_mfma_f32_16x16x32_bf16(ah, bl3, acc3, 0, 0, 0);
        }

        // ---- epilogue: gates, c in regs, stage h tile to LDS ----
        const floatx4 wih = dec ? wihD : wihE;
        const floatx4 bb  = dec ? bD   : bE;
        floatx4 accs[4] = {acc0, acc1, acc2, acc3};
        float px[4];
        #pragma unroll
        for (int nt = 0; nt < 4; ++nt) {
            float x  = xq[nt];
            float i_ = fsig (accs[nt][0] + bb[0] + x * wih[0]);
            float f_ = fsig (accs[nt][1] + bb[1] + x * wih[1]);
            float g_ = ftanh(accs[nt][2] + bb[2] + x * wih[2]);
            float o_ = fsig (accs[nt][3] + bb[3] + x * wih[3]);
            float cv = f_ * creg[nt] + i_ * g_;
            creg[nt] = cv;
            float h  = o_ * ftanh(cv);
            __bf16 hh = (__bf16)h;
            int bl = nt * 16 + lr;
            hstage[bl * 16 + jl] = hh;
            hstage[1024 + bl * 16 + jl] = (__bf16)(h - (float)hh);
            if (dec) {
                float v = h * lw;
                v += __shfl_xor(v, 16);
                v += __shfl_xor(v, 32);
                px[nt] = v;
            }
        }

        __syncthreads();   // hstage complete; xred zero visible

        // coalesced LLC-direct h store: 16-B chunk per thread
        {
            int plane = tid >> 7;
            int q = tid & 127;
            int b2 = q >> 1, half = q & 1;
            const __bf16* src = hstage + plane * 1024 + b2 * 16 + half * 8;
            int4v v = *(const int4v*)src;
            __bf16* base = plane ? houtlo : houthi;
            __bf16* dst = base + (size_t)(nbase + b2) * HID + mx * 16 + half * 8;
            GSTOREX4(dst, v);
        }

        if (dec && lane < 16) {
            #pragma unroll
            for (int nt = 0; nt < 4; ++nt) atomicAdd(&xred[nt * 16 + lr], px[nt]);
        }
        __syncthreads();
        if (dec && tid < 64) {
            atomicAdd(&xacc[(t % 3) * BATCH + nbase + tid], xred[tid]);
        }

        // ---- group barrier: relaxed device-scope atomics, no fences ----
        __builtin_amdgcn_s_waitcnt(0);   // h stores + xacc atomics at LLC
        __syncthreads();
        if (tid == 0) {
            int n = __hip_atomic_fetch_add(arrive, 1, __ATOMIC_RELAXED, __HIP_MEMORY_SCOPE_AGENT);
            if (n == 32 * (s + 1) - 1) {
                __hip_atomic_store(phase, s + 1, __ATOMIC_RELAXED, __HIP_MEMORY_SCOPE_AGENT);
            } else {
                int p;
                do {
                    __builtin_amdgcn_s_sleep(2);
                    p = __hip_atomic_load(phase, __ATOMIC_RELAXED, __HIP_MEMORY_SCOPE_AGENT);
                } while (p < s + 1);
            }
        }
        __syncthreads();
    }

    // tail: out[:, TOUT-1]
    if (mx == 0 && tid < 64) {
        float v = __hip_atomic_load(&xacc[((TOUT - 1) % 3) * BATCH + nbase + tid],
                                    __ATOMIC_RELAXED, __HIP_MEMORY_SCOPE_AGENT) + lb;
        out[(size_t)(nbase + tid) * TOUT + (TOUT - 1)] = v;
    }
}

extern "C" void kernel_launch(void* const* d_in, const int* in_sizes, int n_in,
                              void* d_out, int out_size, void* d_ws, size_t ws_size,
                              hipStream_t stream) {
    const float* inputs  = (const float*)d_in[0];
    const float* enc_Wih = (const float*)d_in[2];
    const float* enc_Whh = (const float*)d_in[3];
    const float* enc_b   = (const float*)d_in[4];
    const float* dec_Wih = (const float*)d_in[5];
    const float* dec_Whh = (const float*)d_in[6];
    const float* dec_b   = (const float*)d_in[7];
    const float* lin_W   = (const float*)d_in[8];
    const float* lin_b   = (const float*)d_in[9];
    float* out = (float*)d_out;

    char* ws = (char*)d_ws;
    const size_t SZ_APK = (size_t)FOUR_H * HID * 2 * sizeof(__bf16);  // 4 MB
    const size_t SZ_V = (size_t)FOUR_H * sizeof(float);
    const size_t SZ_H = (size_t)BATCH * HID * sizeof(__bf16);         // 512 KB

    __bf16* ApkEnc = (__bf16*)(ws);
    __bf16* ApkDec = (__bf16*)(ws + SZ_APK);
    char* p = ws + 2 * SZ_APK;
    float* WihPenc  = (float*)p;  p += SZ_V;
    float* biasPenc = (float*)p;  p += SZ_V;
    float* WihPdec  = (float*)p;  p += SZ_V;
    float* biasPdec = (float*)p;  p += SZ_V;
    float* inputsT  = (float*)p;  p += (size_t)TIN * BATCH * sizeof(float);
    __bf16* h0hi = (__bf16*)p;    p += SZ_H;
    __bf16* h0lo = (__bf16*)p;    p += SZ_H;
    __bf16* h1hi = (__bf16*)p;    p += SZ_H;
    __bf16* h1lo = (__bf16*)p;    p += SZ_H;
    float* xacc  = (float*)p;     p += 3 * BATCH * sizeof(float);
    int* barrier_ws = (int*)p;    p += 1024 * sizeof(int);

    pack_w<<<512, 256, 0, stream>>>(enc_Whh, ApkEnc);
    pack_w<<<512, 256, 0, stream>>>(dec_Whh, ApkDec);
    pack_v<<<8, 256, 0, stream>>>(enc_Wih, enc_b, WihPenc, biasPenc);
    pack_v<<<8, 256, 0, stream>>>(dec_Wih, dec_b, WihPdec, biasPdec);
    transpose_in<<<1024, 256, 0, stream>>>(inputs, inputsT);
    hipMemsetAsync(h0hi, 0, SZ_H, stream);
    hipMemsetAsync(h0lo, 0, SZ_H, stream);
    hipMemsetAsync(xacc, 0, 3 * BATCH * sizeof(float), stream);
    hipMemsetAsync(barrier_ws, 0, 1024 * sizeof(int), stream);

    const int shmem = 131072 + 4096 + 256;   // A-frags + hstage + xred
    hipFuncSetAttribute((const void*)lstm_persistent,
                        hipFuncAttributeMaxDynamicSharedMemorySize, shmem);

    void* args[] = {
        (void*)&ApkEnc, (void*)&ApkDec,
        (void*)&WihPenc, (void*)&biasPenc, (void*)&WihPdec, (void*)&biasPdec,
        (void*)&inputsT, (void*)&lin_W, (void*)&lin_b,
        (void*)&h0hi, (void*)&h0lo, (void*)&h1hi, (void*)&h1lo,
        (void*)&xacc, (void*)&barrier_ws, (void*)&out
    };
    hipLaunchCooperativeKernel((void*)lstm_persistent, dim3(256), dim3(256),
                               args, shmem, stream);
}

// Round 7
// 5029.642 us; speedup vs baseline: 2.1462x; 2.1462x over previous
//
#include <hip/hip_runtime.h>
#include <math.h>

#define HID    512
#define BATCH  512
#define TIN    512
#define TOUT   128
#define FOUR_H 2048
#define STEPS  (TIN + TOUT)

typedef __bf16 bf16x8 __attribute__((ext_vector_type(8)));
typedef float floatx4 __attribute__((ext_vector_type(4)));
typedef int   int4v   __attribute__((ext_vector_type(4)));

// LLC-direct (bypass L1+L2) 16-B load/store (coherence point = Infinity Cache).
#define GLOADX4(dst, p) \
    asm volatile("global_load_dwordx4 %0, %1, off sc0 sc1" : "=v"(dst) : "v"(p))
#define GSTOREX4(p, v) \
    asm volatile("global_store_dwordx4 %0, %1, off sc0 sc1" :: "v"(p), "v"(v) : "memory")
// exact-count wait tying the two staging registers consumed by the ds_write
#define WAITVN2(N, a, b) \
    asm volatile("s_waitcnt vmcnt(" #N ")" : "+v"(a), "+v"(b))

__device__ __forceinline__ float fsig(float x) {
    return __builtin_amdgcn_rcpf(1.0f + __expf(-x));
}
__device__ __forceinline__ float ftanh(float x) {
    return 1.0f - 2.0f * __builtin_amdgcn_rcpf(1.0f + __expf(2.0f * x));
}

// ---------- prep: pack Whh into MFMA-fragment order, bf16 hi/lo planes.
// (layout + numerics verified R6: conflict-free ds_read_b128, absmax 9.5e-7)
__global__ __launch_bounds__(256) void pack_w(
    const float* __restrict__ W, __bf16* __restrict__ Apk)
{
    int tid = blockIdx.x * 256 + threadIdx.x;   // 131072 threads
    int mp  = tid >> 6;                         // m' in [0,2048)
    int kg  = tid & 63;                         // k-group of 8
    int g   = mp & 3;
    int j   = mp >> 2;
    int r   = g * HID + j;
    int mx    = mp >> 6;
    int w     = (mp >> 4) & 3;
    int lr    = mp & 15;
    int chunk = kg >> 2;
    int lq    = kg & 3;
    int lane  = lq * 16 + lr;
    const float* src = W + (size_t)r * HID + kg * 8;
    size_t offHi = ((size_t)(mx * 128 + w * 32 + chunk * 2 + 0) * 512) + lane * 8;
    size_t offLo = ((size_t)(mx * 128 + w * 32 + chunk * 2 + 1) * 512) + lane * 8;
    __bf16 hibuf[8], lobuf[8];
    #pragma unroll
    for (int i = 0; i < 8; ++i) {
        float x = src[i];
        __bf16 hi = (__bf16)x;
        hibuf[i] = hi;
        lobuf[i] = (__bf16)(x - (float)hi);
    }
    *(bf16x8*)(Apk + offHi) = *(bf16x8*)hibuf;
    *(bf16x8*)(Apk + offLo) = *(bf16x8*)lobuf;
}

__global__ __launch_bounds__(256) void pack_v(
    const float* __restrict__ Wih, const float* __restrict__ b,
    float* __restrict__ WihP, float* __restrict__ bP)
{
    int mp = blockIdx.x * 256 + threadIdx.x;
    int g  = mp & 3;
    int j  = mp >> 2;
    int r  = g * HID + j;
    WihP[mp] = Wih[r];
    bP[mp]   = b[r];
}

__global__ __launch_bounds__(256) void transpose_in(
    const float* __restrict__ in, float* __restrict__ outT)
{
    int idx = blockIdx.x * 256 + threadIdx.x;
    int t = idx >> 9, b = idx & 511;
    outT[idx] = in[(size_t)b * TIN + t];
}

// ---------- persistent cooperative kernel ----------
// grid 256 = 32 mx x 8 by; block 256 = 4 waves; 1 block/CU (LDS-limited).
// R6 finding: all 4 waves loaded IDENTICAL B fragments -> 512 KB/CU/step of
// LLC-direct traffic; HW throughput limit on sc1 loads made pipeline depth
// irrelevant. R7: block cooperatively stages each 8 KB B-chunk into a 3-slot
// LDS ring ONCE (128 KB/CU/step), waves ds_read fragments from it.
__global__ __launch_bounds__(256, 1) void lstm_persistent(
    const __bf16* __restrict__ ApkEnc,   // [32][128][512] bf16 fragment order, 4 MB
    const __bf16* __restrict__ ApkDec,
    const float* __restrict__ WihPenc, const float* __restrict__ biasPenc,
    const float* __restrict__ WihPdec, const float* __restrict__ biasPdec,
    const float* __restrict__ inputsT,
    const float* __restrict__ linW, const float* __restrict__ linb,
    __bf16* __restrict__ h0hi, __bf16* __restrict__ h0lo,
    __bf16* __restrict__ h1hi, __bf16* __restrict__ h1lo,
    float* __restrict__ xacc,        // [3][BATCH] rotating decoder-feedback accum
    int* __restrict__ barrier_ws,
    float* __restrict__ out)         // [BATCH][TOUT]
{
    extern __shared__ char smem[];
    __bf16* Alds = (__bf16*)smem;                     // 131072 B, fragment order
    char*   Bring = smem + 131072;                    // 3 slots x 8192 B
    __bf16* hstage = (__bf16*)(smem + 131072 + 24576);    // [2][64][16] = 4096 B
    float*  xred = (float*)(smem + 131072 + 24576 + 4096);// [64]

    const int tid  = threadIdx.x;
    const int lane = tid & 63;
    const int w    = tid >> 6;
    const int lr   = lane & 15;
    const int lq   = lane >> 4;
    const int by   = blockIdx.x & 7;
    const int mx   = blockIdx.x >> 3;
    const int nbase = by * 64;
    const int mrow0 = mx * 64;
    const int m0    = mrow0 + w * 16 + lq * 4;   // lane's 4 m' rows (C-layout)
    const int jl    = w * 4 + lq;                // local j 0..15

    const floatx4 wihE = *(const floatx4*)(WihPenc + m0);
    const floatx4 bE   = *(const floatx4*)(biasPenc + m0);
    const floatx4 wihD = *(const floatx4*)(WihPdec + m0);
    const floatx4 bD   = *(const floatx4*)(biasPdec + m0);
    const float lw = linW[mx * 16 + jl];
    const float lb = linb[0];

    int bn[4];
    #pragma unroll
    for (int nt = 0; nt < 4; ++nt) bn[nt] = nbase + nt * 16 + lr;

    // ---- B-staging constants: thread tid owns (blocal = tid>>2, o = tid&3),
    // one 16-B piece per plane per chunk. Written in B-fragment order:
    //   elem ((nt*2+plane)*64 + o*16 + (blocal&15)) * 8, nt = blocal>>4.
    const int blocal = tid >> 2;
    const int o      = tid & 3;
    const size_t boff = (size_t)(nbase + blocal) * HID + o * 8;   // + c*32 per chunk
    const int fhiB = ((blocal >> 4) * 1024 + (o * 16 + (blocal & 15)) * 8) * 2; // bytes
    const int floB = fhiB + 1024;                                  // +512 elems

    // stage encoder weights: linear 128 KB copy (normal cached loads, read-only)
    {
        const int4v* srcp = (const int4v*)(ApkEnc + (size_t)mx * 65536);
        int4v* dstp = (int4v*)Alds;
        for (int i = tid; i < 8192; i += 256) dstp[i] = srcp[i];
    }
    __syncthreads();

    float creg[4] = {0.f, 0.f, 0.f, 0.f};

    int* arrive = barrier_ws + by * 32;
    int* phase  = barrier_ws + 512 + by * 32;

    // per-lane LDS fragment bases
    const __bf16* aBase = Alds + (size_t)w * 16384 + (size_t)lane * 8;
    const int laneB = lane * 16;   // byte offset of this lane's B fragment piece

    for (int s = 0; s < STEPS; ++s) {
        const bool dec = (s >= TIN);
        const int  t   = s - TIN;

        if (s == TIN) {
            const int4v* srcp = (const int4v*)(ApkDec + (size_t)mx * 65536);
            int4v* dstp = (int4v*)Alds;
            for (int i = tid; i < 8192; i += 256) dstp[i] = srcp[i];
            __syncthreads();
        }

        const __bf16* hinhi = (s & 1) ? h1hi : h0hi;
        const __bf16* hinlo = (s & 1) ? h1lo : h0lo;
        __bf16* houthi = (s & 1) ? h0hi : h1hi;
        __bf16* houtlo = (s & 1) ? h0lo : h1lo;

        const __bf16* ghi = hinhi + boff;
        const __bf16* glo = hinlo + boff;

        // ---- staging pipeline prologue: issue chunks 0,1 ----
        int4v st[2][2];
        GLOADX4(st[0][0], ghi);
        GLOADX4(st[0][1], glo);
        GLOADX4(st[1][0], ghi + 32);
        GLOADX4(st[1][1], glo + 32);

        // ---- x_t + decoder bookkeeping (overlaps staging latency) ----
        float xq[4];
        if (dec) {
            if (tid < 64) xred[tid] = 0.f;
            if (mx == 0) {
                if (t >= 1 && tid < 64) {
                    float v = __hip_atomic_load(&xacc[((t - 1) % 3) * BATCH + nbase + tid],
                                                __ATOMIC_RELAXED, __HIP_MEMORY_SCOPE_AGENT) + lb;
                    out[(size_t)(nbase + tid) * TOUT + (t - 1)] = v;
                }
                if (tid >= 64 && tid < 128) {
                    __hip_atomic_store(&xacc[((t + 1) % 3) * BATCH + nbase + (tid - 64)], 0.0f,
                                       __ATOMIC_RELAXED, __HIP_MEMORY_SCOPE_AGENT);
                }
            }
            #pragma unroll
            for (int nt = 0; nt < 4; ++nt)
                xq[nt] = (t == 0) ? inputsT[(TIN - 1) * BATCH + bn[nt]]
                                  : __hip_atomic_load(&xacc[((t - 1) % 3) * BATCH + bn[nt]],
                                                      __ATOMIC_RELAXED, __HIP_MEMORY_SCOPE_AGENT) + lb;
        } else {
            #pragma unroll
            for (int nt = 0; nt < 4; ++nt)
                xq[nt] = inputsT[s * BATCH + bn[nt]];
        }

        // write chunk 0 to ring slot 0 (over-waiting any bookkeeping loads is safe:
        // staging loads are the oldest outstanding)
        WAITVN2(2, st[0][0], st[0][1]);
        *(int4v*)(Bring + fhiB) = st[0][0];
        *(int4v*)(Bring + floB) = st[0][1];

        floatx4 acc0 = {0,0,0,0}, acc1 = {0,0,0,0}, acc2 = {0,0,0,0}, acc3 = {0,0,0,0};

        // ---- K-loop: 16 chunks; cooperative LDS ring, 2-chunk lookahead ----
        #pragma unroll
        for (int it = 0; it < 16; ++it) {
            if (it + 2 < 16) {
                GLOADX4(st[(it + 2) & 1][0], ghi + (it + 2) * 32);
                GLOADX4(st[(it + 2) & 1][1], glo + (it + 2) * 32);
            }
            if (it + 1 < 16) {
                int4v& a = st[(it + 1) & 1][0];
                int4v& b = st[(it + 1) & 1][1];
                if (it + 2 < 16) { WAITVN2(2, a, b); } else { WAITVN2(0, a, b); }
                char* sb = Bring + ((it + 1) % 3) * 8192;
                *(int4v*)(sb + fhiB) = a;
                *(int4v*)(sb + floB) = b;
            }
            __syncthreads();   // chunk `it` (written last iter) now visible

            const __bf16* ap = aBase + it * 1024;
            const char*   bs = Bring + (it % 3) * 8192;
            bf16x8 ah = *(const bf16x8*)(ap);
            bf16x8 al = *(const bf16x8*)(ap + 512);
            bf16x8 bh0 = *(const bf16x8*)(bs + 0 * 2048 + laneB);
            bf16x8 bl0 = *(const bf16x8*)(bs + 0 * 2048 + 1024 + laneB);
            bf16x8 bh1 = *(const bf16x8*)(bs + 1 * 2048 + laneB);
            bf16x8 bl1 = *(const bf16x8*)(bs + 1 * 2048 + 1024 + laneB);
            bf16x8 bh2 = *(const bf16x8*)(bs + 2 * 2048 + laneB);
            bf16x8 bl2 = *(const bf16x8*)(bs + 2 * 2048 + 1024 + laneB);
            bf16x8 bh3 = *(const bf16x8*)(bs + 3 * 2048 + laneB);
            bf16x8 bl3 = *(const bf16x8*)(bs + 3 * 2048 + 1024 + laneB);

            acc0 = __builtin_amdgcn_mfma_f32_16x16x32_bf16(ah, bh0, acc0, 0, 0, 0);
            acc1 = __builtin_amdgcn_mfma_f32_16x16x32_bf16(ah, bh1, acc1, 0, 0, 0);
            acc2 = __builtin_amdgcn_mfma_f32_16x16x32_bf16(ah, bh2, acc2, 0, 0, 0);
            acc3 = __builtin_amdgcn_mfma_f32_16x16x32_bf16(ah, bh3, acc3, 0, 0, 0);
            acc0 = __builtin_amdgcn_mfma_f32_16x16x32_bf16(al, bh0, acc0, 0, 0, 0);
            acc1 = __builtin_amdgcn_mfma_f32_16x16x32_bf16(al, bh1, acc1, 0, 0, 0);
            acc2 = __builtin_amdgcn_mfma_f32_16x16x32_bf16(al, bh2, acc2, 0, 0, 0);
            acc3 = __builtin_amdgcn_mfma_f32_16x16x32_bf16(al, bh3, acc3, 0, 0, 0);
            acc0 = __builtin_amdgcn_mfma_f32_16x16x32_bf16(ah, bl0, acc0, 0, 0, 0);
            acc1 = __builtin_amdgcn_mfma_f32_16x16x32_bf16(ah, bl1, acc1, 0, 0, 0);
            acc2 = __builtin_amdgcn_mfma_f32_16x16x32_bf16(ah, bl2, acc2, 0, 0, 0);
            acc3 = __builtin_amdgcn_mfma_f32_16x16x32_bf16(ah, bl3, acc3, 0, 0, 0);
        }

        // ---- epilogue: gates, c in regs, stage h tile to LDS ----
        const floatx4 wih = dec ? wihD : wihE;
        const floatx4 bb  = dec ? bD   : bE;
        floatx4 accs[4] = {acc0, acc1, acc2, acc3};
        float px[4];
        #pragma unroll
        for (int nt = 0; nt < 4; ++nt) {
            float x  = xq[nt];
            float i_ = fsig (accs[nt][0] + bb[0] + x * wih[0]);
            float f_ = fsig (accs[nt][1] + bb[1] + x * wih[1]);
            float g_ = ftanh(accs[nt][2] + bb[2] + x * wih[2]);
            float o_ = fsig (accs[nt][3] + bb[3] + x * wih[3]);
            float cv = f_ * creg[nt] + i_ * g_;
            creg[nt] = cv;
            float h  = o_ * ftanh(cv);
            __bf16 hh = (__bf16)h;
            int bl = nt * 16 + lr;
            hstage[bl * 16 + jl] = hh;
            hstage[1024 + bl * 16 + jl] = (__bf16)(h - (float)hh);
            if (dec) {
                float v = h * lw;
                v += __shfl_xor(v, 16);
                v += __shfl_xor(v, 32);
                px[nt] = v;
            }
        }

        __syncthreads();   // hstage complete

        // coalesced LLC-direct h store: 16-B chunk per thread
        {
            int plane = tid >> 7;
            int q = tid & 127;
            int b2 = q >> 1, half = q & 1;
            const __bf16* src = hstage + plane * 1024 + b2 * 16 + half * 8;
            int4v v = *(const int4v*)src;
            __bf16* base = plane ? houtlo : houthi;
            __bf16* dst = base + (size_t)(nbase + b2) * HID + mx * 16 + half * 8;
            GSTOREX4(dst, v);
        }

        if (dec && lane < 16) {
            #pragma unroll
            for (int nt = 0; nt < 4; ++nt) atomicAdd(&xred[nt * 16 + lr], px[nt]);
        }
        __syncthreads();
        if (dec && tid < 64) {
            atomicAdd(&xacc[(t % 3) * BATCH + nbase + tid], xred[tid]);
        }

        // ---- group barrier: relaxed device-scope atomics, no fences ----
        __builtin_amdgcn_s_waitcnt(0);   // h stores + xacc atomics at LLC
        __syncthreads();
        if (tid == 0) {
            int n = __hip_atomic_fetch_add(arrive, 1, __ATOMIC_RELAXED, __HIP_MEMORY_SCOPE_AGENT);
            if (n == 32 * (s + 1) - 1) {
                __hip_atomic_store(phase, s + 1, __ATOMIC_RELAXED, __HIP_MEMORY_SCOPE_AGENT);
            } else {
                int p;
                do {
                    __builtin_amdgcn_s_sleep(2);
                    p = __hip_atomic_load(phase, __ATOMIC_RELAXED, __HIP_MEMORY_SCOPE_AGENT);
                } while (p < s + 1);
            }
        }
        __syncthreads();
    }

    // tail: out[:, TOUT-1]
    if (mx == 0 && tid < 64) {
        float v = __hip_atomic_load(&xacc[((TOUT - 1) % 3) * BATCH + nbase + tid],
                                    __ATOMIC_RELAXED, __HIP_MEMORY_SCOPE_AGENT) + lb;
        out[(size_t)(nbase + tid) * TOUT + (TOUT - 1)] = v;
    }
}

extern "C" void kernel_launch(void* const* d_in, const int* in_sizes, int n_in,
                              void* d_out, int out_size, void* d_ws, size_t ws_size,
                              hipStream_t stream) {
    const float* inputs  = (const float*)d_in[0];
    const float* enc_Wih = (const float*)d_in[2];
    const float* enc_Whh = (const float*)d_in[3];
    const float* enc_b   = (const float*)d_in[4];
    const float* dec_Wih = (const float*)d_in[5];
    const float* dec_Whh = (const float*)d_in[6];
    const float* dec_b   = (const float*)d_in[7];
    const float* lin_W   = (const float*)d_in[8];
    const float* lin_b   = (const float*)d_in[9];
    float* out = (float*)d_out;

    char* ws = (char*)d_ws;
    const size_t SZ_APK = (size_t)FOUR_H * HID * 2 * sizeof(__bf16);  // 4 MB
    const size_t SZ_V = (size_t)FOUR_H * sizeof(float);
    const size_t SZ_H = (size_t)BATCH * HID * sizeof(__bf16);         // 512 KB

    __bf16* ApkEnc = (__bf16*)(ws);
    __bf16* ApkDec = (__bf16*)(ws + SZ_APK);
    char* p = ws + 2 * SZ_APK;
    float* WihPenc  = (float*)p;  p += SZ_V;
    float* biasPenc = (float*)p;  p += SZ_V;
    float* WihPdec  = (float*)p;  p += SZ_V;
    float* biasPdec = (float*)p;  p += SZ_V;
    float* inputsT  = (float*)p;  p += (size_t)TIN * BATCH * sizeof(float);
    __bf16* h0hi = (__bf16*)p;    p += SZ_H;
    __bf16* h0lo = (__bf16*)p;    p += SZ_H;
    __bf16* h1hi = (__bf16*)p;    p += SZ_H;
    __bf16* h1lo = (__bf16*)p;    p += SZ_H;
    float* xacc  = (float*)p;     p += 3 * BATCH * sizeof(float);
    int* barrier_ws = (int*)p;    p += 1024 * sizeof(int);

    pack_w<<<512, 256, 0, stream>>>(enc_Whh, ApkEnc);
    pack_w<<<512, 256, 0, stream>>>(dec_Whh, ApkDec);
    pack_v<<<8, 256, 0, stream>>>(enc_Wih, enc_b, WihPenc, biasPenc);
    pack_v<<<8, 256, 0, stream>>>(dec_Wih, dec_b, WihPdec, biasPdec);
    transpose_in<<<1024, 256, 0, stream>>>(inputs, inputsT);
    hipMemsetAsync(h0hi, 0, SZ_H, stream);
    hipMemsetAsync(h0lo, 0, SZ_H, stream);
    hipMemsetAsync(xacc, 0, 3 * BATCH * sizeof(float), stream);
    hipMemsetAsync(barrier_ws, 0, 1024 * sizeof(int), stream);

    const int shmem = 131072 + 24576 + 4096 + 256;   // A + B-ring + hstage + xred
    hipFuncSetAttribute((const void*)lstm_persistent,
                        hipFuncAttributeMaxDynamicSharedMemorySize, shmem);

    void* args[] = {
        (void*)&ApkEnc, (void*)&ApkDec,
        (void*)&WihPenc, (void*)&biasPenc, (void*)&WihPdec, (void*)&biasPdec,
        (void*)&inputsT, (void*)&lin_W, (void*)&lin_b,
        (void*)&h0hi, (void*)&h0lo, (void*)&h1hi, (void*)&h1lo,
        (void*)&xacc, (void*)&barrier_ws, (void*)&out
    };
    hipLaunchCooperativeKernel((void*)lstm_persistent, dim3(256), dim3(256),
                               args, shmem, stream);
}

// Round 9
// 4471.150 us; speedup vs baseline: 2.4143x; 1.1249x over previous
//
#include <hip/hip_runtime.h>
#include <math.h>

#define HID    512
#define BATCH  512
#define TIN    512
#define TOUT   128
#define FOUR_H 2048
#define STEPS  (TIN + TOUT)

typedef __bf16 bf16x8 __attribute__((ext_vector_type(8)));
typedef float floatx4 __attribute__((ext_vector_type(4)));
typedef int   int4v   __attribute__((ext_vector_type(4)));

// LLC-direct (bypass L1+L2) -- for h exchange (coherence point = Infinity Cache)
#define GLOADX4_SC(dst, p) \
    asm volatile("global_load_dwordx4 %0, %1, off sc0 sc1" : "=v"(dst) : "v"(p))
#define GSTOREX4_SC(p, v) \
    asm volatile("global_store_dwordx4 %0, %1, off sc0 sc1" :: "v"(p), "v"(v) : "memory")
// normal cached load -- for read-only streamed A (hits XCD L2)
#define GLOADX4_C(dst, p) \
    asm volatile("global_load_dwordx4 %0, %1, off" : "=v"(dst) : "v"(p))
// exact-count waits, tying the consumed registers
#define WAIT_T1(N, r) asm volatile("s_waitcnt vmcnt(" #N ")" : "+v"(r))
#define WAIT_T4(N, B) asm volatile("s_waitcnt vmcnt(" #N ")" \
    : "+v"((B)[0]), "+v"((B)[1]), "+v"((B)[2]), "+v"((B)[3]))

__device__ __forceinline__ float fsig(float x) {
    return __builtin_amdgcn_rcpf(1.0f + __expf(-x));
}
__device__ __forceinline__ float ftanh(float x) {
    return 1.0f - 2.0f * __builtin_amdgcn_rcpf(1.0f + __expf(2.0f * x));
}

// ---------- prep: pack Whh into blocked MFMA A-fragment order, bf16 hi/lo.
// m' = 4*j+g (row r = g*512+j); blk = m'>>7 (16 blocks x 128 rows),
// rg = (m'>>4)&7 (8 row-groups of 16), lr = m'&15; chunk = k>>5, lq=(k>>3)&3,
// lane = lq*16+lr.  elem-off = ((((blk*8+rg)*16+chunk)*2+pl)*512 + lane*8).
// Fragment scheme identical to the R6/R7-verified layout, just re-blocked.
__global__ __launch_bounds__(256) void pack_w(
    const float* __restrict__ W, __bf16* __restrict__ Apk)
{
    int tid = blockIdx.x * 256 + threadIdx.x;   // 131072 threads
    int mp  = tid >> 6;                         // m' in [0,2048)
    int kg  = tid & 63;                         // k-group of 8
    int g   = mp & 3;
    int j   = mp >> 2;
    int r   = g * HID + j;
    int blk   = mp >> 7;
    int rg    = (mp >> 4) & 7;
    int lr    = mp & 15;
    int chunk = kg >> 2;
    int lq    = kg & 3;
    int lane  = lq * 16 + lr;
    const float* src = W + (size_t)r * HID + kg * 8;
    size_t offHi = ((size_t)(((blk * 8 + rg) * 16 + chunk) * 2 + 0) * 512) + lane * 8;
    size_t offLo = ((size_t)(((blk * 8 + rg) * 16 + chunk) * 2 + 1) * 512) + lane * 8;
    __bf16 hibuf[8], lobuf[8];
    #pragma unroll
    for (int i = 0; i < 8; ++i) {
        float x = src[i];
        __bf16 hi = (__bf16)x;
        hibuf[i] = hi;
        lobuf[i] = (__bf16)(x - (float)hi);
    }
    *(bf16x8*)(Apk + offHi) = *(bf16x8*)hibuf;
    *(bf16x8*)(Apk + offLo) = *(bf16x8*)lobuf;
}

__global__ __launch_bounds__(256) void pack_v(
    const float* __restrict__ Wih, const float* __restrict__ b,
    float* __restrict__ WihP, float* __restrict__ bP)
{
    int mp = blockIdx.x * 256 + threadIdx.x;
    int g  = mp & 3;
    int j  = mp >> 2;
    int r  = g * HID + j;
    WihP[mp] = Wih[r];
    bP[mp]   = b[r];
}

__global__ __launch_bounds__(256) void transpose_in(
    const float* __restrict__ in, float* __restrict__ outT)
{
    int idx = blockIdx.x * 256 + threadIdx.x;
    int t = idx >> 9, b = idx & 511;
    outT[idx] = in[(size_t)b * TIN + t];
}

// ---------- persistent cooperative kernel ----------
// grid 256 = 16 blk (128 m') x 16 by (32 b); block 256 = 4 waves; 1 block/CU.
// R4-R7 finding: h-read bytes are the wall (~10-13 B/cyc/CU sc1 / ~7-8 TB/s LLC,
// pipeline depth irrelevant). R9 halves per-CU h-panel (64 KB) and fan-out (16).
// Waves 0,1: A rows 0-63 from LDS; waves 2,3: A rows 64-127 streamed L2-cached.
// Wave owns 32 m' x 32 b full-K -> no cross-wave reduction. h panel layout
// [by][chunk][nt][pl][lane]x16B: staging thread tid <-> piece tid (coalesced sc1
// reads, conflict-free ds_writes); producer (blk,by) owns exactly chunk blk.
__global__ __launch_bounds__(256, 1) void lstm_persistent(
    const __bf16* __restrict__ ApkEnc,   // [16 blk][8 rg][16 ch][2 pl][512], 4 MB
    const __bf16* __restrict__ ApkDec,
    const float* __restrict__ WihPenc, const float* __restrict__ biasPenc,
    const float* __restrict__ WihPdec, const float* __restrict__ biasPdec,
    const float* __restrict__ inputsT,
    const float* __restrict__ linW, const float* __restrict__ linb,
    __bf16* __restrict__ h0,         // [16 by][16 ch][256 piece][8] = 1 MB
    __bf16* __restrict__ h1,
    float* __restrict__ xacc,        // [3][BATCH] rotating decoder-feedback accum
    int* __restrict__ barrier_ws,
    float* __restrict__ out)         // [BATCH][TOUT]
{
    extern __shared__ char smem[];
    __bf16* Alds   = (__bf16*)smem;                    // 131072 B (A rows 0-63 hi/lo)
    char*   Bring  = smem + 131072;                    // 4 slots x 4096 B
    __bf16* hstage = (__bf16*)(smem + 147456);         // [2 pl][32 b][32 j] = 4096 B
    float*  xred   = (float*)(smem + 151552);          // [32]

    const int tid  = threadIdx.x;
    const int lane = tid & 63;
    const int w    = tid >> 6;
    const int lr   = lane & 15;
    const int lq   = lane >> 4;
    const int by   = blockIdx.x >> 4;       // 16 batch groups
    const int blk  = blockIdx.x & 15;       // 16 m' blocks (blk%8 = XCD heuristic)
    const int nbase = by * 32;
    const int rgbase = 2 * w;               // wave w owns row-groups {2w, 2w+1}
    const bool STREAM = (w >= 2);           // rg 4..7 streamed from L2

    // lane's packed-m' base for (mb): blk*128 + (rgbase+mb)*16 + lq*4
    const int m0a = blk * 128 + (rgbase + 0) * 16 + lq * 4;
    const int m0b = blk * 128 + (rgbase + 1) * 16 + lq * 4;
    const floatx4 wihE[2] = { *(const floatx4*)(WihPenc + m0a), *(const floatx4*)(WihPenc + m0b) };
    const floatx4 bE[2]   = { *(const floatx4*)(biasPenc + m0a), *(const floatx4*)(biasPenc + m0b) };
    const floatx4 wihD[2] = { *(const floatx4*)(WihPdec + m0a), *(const floatx4*)(WihPdec + m0b) };
    const floatx4 bD[2]   = { *(const floatx4*)(biasPdec + m0a), *(const floatx4*)(biasPdec + m0b) };
    const float lw[2] = { linW[m0a >> 2], linW[m0b >> 2] };   // j = m'>>2
    const float lb = linb[0];

    int bn[2];
    #pragma unroll
    for (int nt = 0; nt < 2; ++nt) bn[nt] = nbase + nt * 16 + lr;

    // stage resident A half (rg 0..3): linear 128 KB copy
    {
        const int4v* srcp = (const int4v*)(ApkEnc + (size_t)blk * 131072);
        int4v* dstp = (int4v*)Alds;
        for (int i = tid; i < 8192; i += 256) dstp[i] = srcp[i];
    }
    __syncthreads();

    float creg[2][2] = {{0.f, 0.f}, {0.f, 0.f}};

    int* arrive = barrier_ws + by * 32;
    int* phase  = barrier_ws + 512 + by * 32;

    for (int s = 0; s < STEPS; ++s) {
        const bool dec = (s >= TIN);
        const int  t   = s - TIN;
        const __bf16* Acur = dec ? ApkDec : ApkEnc;

        if (s == TIN) {
            const int4v* srcp = (const int4v*)(ApkDec + (size_t)blk * 131072);
            int4v* dstp = (int4v*)Alds;
            for (int i = tid; i < 8192; i += 256) dstp[i] = srcp[i];
            __syncthreads();
        }

        const __bf16* hin  = (s & 1) ? h1 : h0;
        __bf16*       hout = (s & 1) ? h0 : h1;
        const __bf16* srcB = hin + (size_t)by * 32768 + tid * 8;    // + chunk*2048
        const __bf16* Ag   = Acur + (size_t)blk * 131072;

        // ---- bookkeeping first (oldest vmem, drained by any later wait) ----
        float xq[2];
        if (dec) {
            if (tid < 32) xred[tid] = 0.f;
            if (blk == 0) {
                if (t >= 1 && tid < 32) {
                    float v = __hip_atomic_load(&xacc[((t - 1) % 3) * BATCH + nbase + tid],
                                                __ATOMIC_RELAXED, __HIP_MEMORY_SCOPE_AGENT) + lb;
                    out[(size_t)(nbase + tid) * TOUT + (t - 1)] = v;
                }
                if (tid >= 32 && tid < 64) {
                    __hip_atomic_store(&xacc[((t + 1) % 3) * BATCH + nbase + (tid - 32)], 0.0f,
                                       __ATOMIC_RELAXED, __HIP_MEMORY_SCOPE_AGENT);
                }
            }
            #pragma unroll
            for (int nt = 0; nt < 2; ++nt)
                xq[nt] = (t == 0) ? inputsT[(TIN - 1) * BATCH + bn[nt]]
                                  : __hip_atomic_load(&xacc[((t - 1) % 3) * BATCH + bn[nt]],
                                                      __ATOMIC_RELAXED, __HIP_MEMORY_SCOPE_AGENT) + lb;
        } else {
            #pragma unroll
            for (int nt = 0; nt < 2; ++nt)
                xq[nt] = inputsT[s * BATCH + bn[nt]];
        }
        asm volatile("" ::: "memory");   // pin bookkeeping vmem above staging asm

        // ---- prologue issues (age order B0 < B1 < A0 < B2, matching steady) ----
        int4v st[4];
        int4v areg[2][4];
        GLOADX4_SC(st[0], srcB + 0 * 2048);
        GLOADX4_SC(st[1], srcB + 1 * 2048);
        if (STREAM) {
            #pragma unroll
            for (int mb = 0; mb < 2; ++mb)
                #pragma unroll
                for (int pl = 0; pl < 2; ++pl)
                    GLOADX4_C(areg[0][mb * 2 + pl],
                              Ag + (size_t)((((rgbase + mb) * 16 + 0) * 2 + pl) * 512) + lane * 8);
        }
        GLOADX4_SC(st[2], srcB + 2 * 2048);

        floatx4 acc[2][2];
        #pragma unroll
        for (int mb = 0; mb < 2; ++mb)
            #pragma unroll
            for (int nt = 0; nt < 2; ++nt) acc[mb][nt] = floatx4{0.f, 0.f, 0.f, 0.f};

        // ---- K-loop: 16 chunks. (a) wait+write B(it); (b') issue A(it+1), B(it+3);
        // (c) sync; (d) wait A(it), ds_read frags, 12 MFMAs.
        // vmcnt tables derived from exact instruction age order (see R9 notes).
        #pragma unroll
        for (int it = 0; it < 16; ++it) {
            // (a) wait B(it) resident, write ring slot
            if (STREAM) {
                if      (it <= 13) { WAIT_T1(6, st[it & 3]); }
                else if (it == 14) { WAIT_T1(5, st[it & 3]); }
                else               { WAIT_T1(4, st[it & 3]); }
            } else {
                if      (it <= 13) { WAIT_T1(2, st[it & 3]); }
                else if (it == 14) { WAIT_T1(1, st[it & 3]); }
                else               { WAIT_T1(0, st[it & 3]); }
            }
            *(int4v*)(Bring + (it & 3) * 4096 + tid * 16) = st[it & 3];

            // (b') issue A(it+1) then B(it+3)
            if (STREAM && it + 1 < 16) {
                #pragma unroll
                for (int mb = 0; mb < 2; ++mb)
                    #pragma unroll
                    for (int pl = 0; pl < 2; ++pl)
                        GLOADX4_C(areg[(it + 1) & 1][mb * 2 + pl],
                                  Ag + (size_t)((((rgbase + mb) * 16 + (it + 1)) * 2 + pl) * 512) + lane * 8);
            }
            if (it + 3 < 16) GLOADX4_SC(st[(it + 3) & 3], srcB + (it + 3) * 2048);

            __syncthreads();   // chunk `it` visible in ring

            // (d) A fragments
            bf16x8 ah[2], al[2];
            if (STREAM) {
                if      (it <= 12) { WAIT_T4(6, areg[it & 1]); }
                else if (it == 13) { WAIT_T4(5, areg[it & 1]); }
                else if (it == 14) { WAIT_T4(4, areg[it & 1]); }
                else               { WAIT_T4(0, areg[it & 1]); }
                #pragma unroll
                for (int mb = 0; mb < 2; ++mb) {
                    ah[mb] = __builtin_bit_cast(bf16x8, areg[it & 1][mb * 2 + 0]);
                    al[mb] = __builtin_bit_cast(bf16x8, areg[it & 1][mb * 2 + 1]);
                }
            } else {
                #pragma unroll
                for (int mb = 0; mb < 2; ++mb) {
                    const char* ap = (const char*)Alds
                        + (((rgbase + mb) * 16 + it) * 2) * 1024 + lane * 16;
                    ah[mb] = *(const bf16x8*)(ap);
                    al[mb] = *(const bf16x8*)(ap + 1024);
                }
            }

            const char* bs = Bring + (it & 3) * 4096;
            bf16x8 bh0 = *(const bf16x8*)(bs + (0 * 128 + 0 * 64 + lane) * 16);
            bf16x8 bl0 = *(const bf16x8*)(bs + (0 * 128 + 1 * 64 + lane) * 16);
            bf16x8 bh1 = *(const bf16x8*)(bs + (1 * 128 + 0 * 64 + lane) * 16);
            bf16x8 bl1 = *(const bf16x8*)(bs + (1 * 128 + 1 * 64 + lane) * 16);

            #pragma unroll
            for (int mb = 0; mb < 2; ++mb) {
                acc[mb][0] = __builtin_amdgcn_mfma_f32_16x16x32_bf16(ah[mb], bh0, acc[mb][0], 0, 0, 0);
                acc[mb][1] = __builtin_amdgcn_mfma_f32_16x16x32_bf16(ah[mb], bh1, acc[mb][1], 0, 0, 0);
                acc[mb][0] = __builtin_amdgcn_mfma_f32_16x16x32_bf16(al[mb], bh0, acc[mb][0], 0, 0, 0);
                acc[mb][1] = __builtin_amdgcn_mfma_f32_16x16x32_bf16(al[mb], bh1, acc[mb][1], 0, 0, 0);
                acc[mb][0] = __builtin_amdgcn_mfma_f32_16x16x32_bf16(ah[mb], bl0, acc[mb][0], 0, 0, 0);
                acc[mb][1] = __builtin_amdgcn_mfma_f32_16x16x32_bf16(ah[mb], bl1, acc[mb][1], 0, 0, 0);
            }
        }

        // ---- epilogue: gates, c in regs, stage h tile to LDS ----
        const floatx4* wih = dec ? wihD : wihE;
        const floatx4* bb  = dec ? bD   : bE;
        float px[2] = {0.f, 0.f};
        #pragma unroll
        for (int mb = 0; mb < 2; ++mb) {
            const int jlocal = (rgbase + mb) * 4 + lq;   // 0..31
            #pragma unroll
            for (int nt = 0; nt < 2; ++nt) {
                float x  = xq[nt];
                float i_ = fsig (acc[mb][nt][0] + bb[mb][0] + x * wih[mb][0]);
                float f_ = fsig (acc[mb][nt][1] + bb[mb][1] + x * wih[mb][1]);
                float g_ = ftanh(acc[mb][nt][2] + bb[mb][2] + x * wih[mb][2]);
                float o_ = fsig (acc[mb][nt][3] + bb[mb][3] + x * wih[mb][3]);
                float cv = f_ * creg[mb][nt] + i_ * g_;
                creg[mb][nt] = cv;
                float h  = o_ * ftanh(cv);
                __bf16 hh = (__bf16)h;
                int bl = nt * 16 + lr;
                hstage[bl * 32 + jlocal] = hh;                  // pl 0
                hstage[1024 + bl * 32 + jlocal] = (__bf16)(h - (float)hh);  // pl 1
                if (dec) {
                    float v = h * lw[mb];
                    px[nt] += v;
                }
            }
        }
        if (dec) {
            #pragma unroll
            for (int nt = 0; nt < 2; ++nt) {
                px[nt] += __shfl_xor(px[nt], 16);
                px[nt] += __shfl_xor(px[nt], 32);   // sum over lq
            }
        }

        __syncthreads();   // hstage complete; xred zero visible

        // producer h store: thread tid -> piece tid of chunk `blk` (coalesced sc1)
        {
            int nt = tid >> 7, pl = (tid >> 6) & 1, ln = tid & 63;
            int kq = ln >> 4, lrp = ln & 15;
            const char* src = (const char*)hstage + pl * 2048 + (nt * 16 + lrp) * 64 + kq * 16;
            int4v v = *(const int4v*)src;
            __bf16* dst = hout + (size_t)by * 32768 + blk * 2048 + tid * 8;
            GSTOREX4_SC(dst, v);
        }

        if (dec && lane < 16) {
            #pragma unroll
            for (int nt = 0; nt < 2; ++nt) atomicAdd(&xred[nt * 16 + lr], px[nt]);
        }
        __syncthreads();
        if (dec && tid < 32) {
            atomicAdd(&xacc[(t % 3) * BATCH + nbase + tid], xred[tid]);
        }

        // ---- group barrier (16 blocks sharing by): relaxed device-scope atomics ----
        __builtin_amdgcn_s_waitcnt(0);   // h stores + xacc atomics at LLC
        __syncthreads();
        if (tid == 0) {
            int n = __hip_atomic_fetch_add(arrive, 1, __ATOMIC_RELAXED, __HIP_MEMORY_SCOPE_AGENT);
            if (n == 16 * (s + 1) - 1) {
                __hip_atomic_store(phase, s + 1, __ATOMIC_RELAXED, __HIP_MEMORY_SCOPE_AGENT);
            } else {
                int p;
                do {
                    __builtin_amdgcn_s_sleep(2);
                    p = __hip_atomic_load(phase, __ATOMIC_RELAXED, __HIP_MEMORY_SCOPE_AGENT);
                } while (p < s + 1);
            }
        }
        __syncthreads();
    }

    // tail: out[:, TOUT-1]
    if (blk == 0 && tid < 32) {
        float v = __hip_atomic_load(&xacc[((TOUT - 1) % 3) * BATCH + nbase + tid],
                                    __ATOMIC_RELAXED, __HIP_MEMORY_SCOPE_AGENT) + lb;
        out[(size_t)(nbase + tid) * TOUT + (TOUT - 1)] = v;
    }
}

extern "C" void kernel_launch(void* const* d_in, const int* in_sizes, int n_in,
                              void* d_out, int out_size, void* d_ws, size_t ws_size,
                              hipStream_t stream) {
    const float* inputs  = (const float*)d_in[0];
    const float* enc_Wih = (const float*)d_in[2];
    const float* enc_Whh = (const float*)d_in[3];
    const float* enc_b   = (const float*)d_in[4];
    const float* dec_Wih = (const float*)d_in[5];
    const float* dec_Whh = (const float*)d_in[6];
    const float* dec_b   = (const float*)d_in[7];
    const float* lin_W   = (const float*)d_in[8];
    const float* lin_b   = (const float*)d_in[9];
    float* out = (float*)d_out;

    char* ws = (char*)d_ws;
    const size_t SZ_APK = (size_t)FOUR_H * HID * 2 * sizeof(__bf16);   // 4 MB
    const size_t SZ_V   = (size_t)FOUR_H * sizeof(float);
    const size_t SZ_HF  = (size_t)16 * 16 * 256 * 8 * sizeof(__bf16);  // 1 MB

    __bf16* ApkEnc = (__bf16*)(ws);
    __bf16* ApkDec = (__bf16*)(ws + SZ_APK);
    char* p = ws + 2 * SZ_APK;
    float* WihPenc  = (float*)p;  p += SZ_V;
    float* biasPenc = (float*)p;  p += SZ_V;
    float* WihPdec  = (float*)p;  p += SZ_V;
    float* biasPdec = (float*)p;  p += SZ_V;
    float* inputsT  = (float*)p;  p += (size_t)TIN * BATCH * sizeof(float);
    __bf16* h0 = (__bf16*)p;      p += SZ_HF;
    __bf16* h1 = (__bf16*)p;      p += SZ_HF;
    float* xacc  = (float*)p;     p += 3 * BATCH * sizeof(float);
    int* barrier_ws = (int*)p;    p += 1024 * sizeof(int);

    pack_w<<<512, 256, 0, stream>>>(enc_Whh, ApkEnc);
    pack_w<<<512, 256, 0, stream>>>(dec_Whh, ApkDec);
    pack_v<<<8, 256, 0, stream>>>(enc_Wih, enc_b, WihPenc, biasPenc);
    pack_v<<<8, 256, 0, stream>>>(dec_Wih, dec_b, WihPdec, biasPdec);
    transpose_in<<<1024, 256, 0, stream>>>(inputs, inputsT);
    hipMemsetAsync(h0, 0, SZ_HF, stream);
    hipMemsetAsync(xacc, 0, 3 * BATCH * sizeof(float), stream);
    hipMemsetAsync(barrier_ws, 0, 1024 * sizeof(int), stream);

    const int shmem = 131072 + 16384 + 4096 + 128;   // A + ring + hstage + xred
    hipFuncSetAttribute((const void*)lstm_persistent,
                        hipFuncAttributeMaxDynamicSharedMemorySize, shmem);

    void* args[] = {
        (void*)&ApkEnc, (void*)&ApkDec,
        (void*)&WihPenc, (void*)&biasPenc, (void*)&WihPdec, (void*)&biasPdec,
        (void*)&inputsT, (void*)&lin_W, (void*)&lin_b,
        (void*)&h0, (void*)&h1,
        (void*)&xacc, (void*)&barrier_ws, (void*)&out
    };
    hipLaunchCooperativeKernel((void*)lstm_persistent, dim3(256), dim3(256),
                               args, shmem, stream);
}